// Round 19
// baseline (167.934 us; speedup 1.0000x reference)
//
#include <hip/hip_runtime.h>
#include <cstdint>
#include <cstddef>

typedef __attribute__((ext_vector_type(8))) short short8;
typedef __attribute__((ext_vector_type(8))) unsigned short ushort8;
typedef __attribute__((ext_vector_type(4))) float f32x4;

#define AS1Q const __attribute__((address_space(1)))
#define AS3Q __attribute__((address_space(3)))

constexpr int T_N = 60, IN_N = 520, MOE_RAW_N = 512, MOE_IN_N = 992;
constexpr int HID_N = 752, E_N = 8;
constexpr int K2_N = 6016;            // 8*752 (= 94 K-tiles of 64)
constexpr int KA_N = 1024;            // padded Xm row length (992 -> 1024)
constexpr int SPLITK = 20;            // R11-proven (R18's 10 lost parallelism)
constexpr int PN = 768;               // Y1 / P row pitch (layer-2 path)
constexpr int NT_W2 = 94 * 12;        // conversion tiles for w2 (94 kt x 12 ntile)
constexpr int NT_W3 = 94 * 8;         // conversion tiles for w3

static __device__ __forceinline__ unsigned short f2bf(float f) {
  unsigned int u = __float_as_uint(f);
  return (unsigned short)((u + 0x7fffu + ((u >> 16) & 1u)) >> 16);   // RNE
}
static __device__ __forceinline__ float sigf(float x) {
  return __fdividef(1.f, 1.f + __expf(-x));
}
static __device__ __forceinline__ float tanh_fast(float x) {
  return 2.f * __fdividef(1.f, 1.f + __expf(-2.f * x)) - 1.f;
}

// DPP row-rotate by R within the 16-lane row (pure VALU — no LDS pipe).
template<int R>
static __device__ __forceinline__ float rotf(float v) {
  return __int_as_float(__builtin_amdgcn_update_dpp(
      0, __float_as_int(v), 0x120 | R, 0xF, 0xF, true));
}
static __device__ __forceinline__ void rot8(float (&d)[8], float v) {
  d[0] = v;
  d[1] = rotf<1>(v); d[2] = rotf<2>(v); d[3] = rotf<3>(v);
  d[4] = rotf<4>(v); d[5] = rotf<5>(v); d[6] = rotf<6>(v); d[7] = rotf<7>(v);
}

// ---------------------------------------------------------------------------
// xm_prep: Xm_bf16[b][ (i ^ (b&7)<<3) ] = bf16(Xm[b,i]), rows padded to 1024.
// ---------------------------------------------------------------------------
__global__ __launch_bounds__(256)
void xm_prep(const float* __restrict__ X, unsigned short* __restrict__ XmBf)
{
  const int i = blockIdx.x * 256 + threadIdx.x;   // grid.x=4 -> 0..1023
  const int b = blockIdx.y;
  const float* Xb = X + (size_t)b * (T_N * IN_N);
  float v = 0.f;
  if (i < MOE_RAW_N) {
    v = Xb[(T_N - 1) * IN_N + i];
  } else if (i < MOE_IN_N) {
    const int q = i - MOE_RAW_N;
    v = Xb[(q >> 3) * IN_N + MOE_RAW_N + (q & 7)];
  }
  XmBf[(size_t)b * KA_N + (i ^ ((b & 7) << 3))] = f2bf(v);
}

// ---------------------------------------------------------------------------
// FUSED: GRU (blocks 0..15, LDS-resident weights — R11-proven) +
// expert-separated layer-1 GEMM (blocks 16..207, verbatim R11) +
// NEW blocks 208..255: convert w2/w3 -> bf16 pre-swizzled [n][k] tiles under
// the GRU shadow (48 otherwise-idle CUs). Same f2bf RNE as the old staging
// gather -> gemm2/gemm3 results are BIT-IDENTICAL to R11.
// Target layout: Bsw[n][kt*64 + c*8 + j] = bf16( W[kt*64 + (c^(n&7))*8 + j][n] )
// so a gemm wave stages a 64n x 64k tile with 2 global_load_lds (lane-linear
// dest, per-lane src), and the existing swizzled compute-read is unchanged.
// ---------------------------------------------------------------------------
__global__ __launch_bounds__(256, 1)
void fused_gru_gemm1(const float* __restrict__ X,
                     const float* __restrict__ Wih0, const float* __restrict__ Whh0,
                     const float* __restrict__ bih0, const float* __restrict__ bhh0,
                     const float* __restrict__ Wih1, const float* __restrict__ Whh1,
                     const float* __restrict__ bih1, const float* __restrict__ bhh1,
                     const unsigned short* __restrict__ XmBf,
                     const float* __restrict__ w1,
                     const float* __restrict__ w2, const float* __restrict__ w3,
                     unsigned short* __restrict__ B2sw2,
                     unsigned short* __restrict__ B2sw3,
                     float* __restrict__ Y1, float* __restrict__ Omega)
{
  __shared__ union SM {
    struct { unsigned short Al[2][256][64]; unsigned short Bl[2][64][64]; } g; // 80 KB
    struct { float xl[T_N][256]; float wl[12][8][8]; } r;                      // 63 KB
    struct { unsigned short tl[64][66]; } c;                                   // 8.25 KB
  } sm;

  const int tid  = threadIdx.x;
  const int lane = tid & 63;
  const int wave = tid >> 6;

  if (blockIdx.x >= 208) {
    // ============ conversion branch: w2/w3 -> bf16 swizzled [n][k] ============
    const int cid = blockIdx.x - 208;   // 0..47
    for (int tile = cid; tile < NT_W2 + NT_W3; tile += 48) {
      const float* W; unsigned short* Dst; int N, kt, ntile;
      if (tile < NT_W2) { W = w2; Dst = B2sw2; N = HID_N; kt = tile / 12; ntile = tile % 12; }
      else { const int t2 = tile - NT_W2; W = w3; Dst = B2sw3; N = 512; kt = t2 / 8; ntile = t2 % 8; }
      const int n0 = ntile * 64, k0 = kt * 64;
      // read 64k x 64n (coalesced in n), bf16-convert into LDS
      const int nl = tid & 63;
#pragma unroll
      for (int p = 0; p < 16; ++p) {
        const int kl = (tid >> 6) + p * 4;
        const float v = (n0 + nl < N) ? W[(size_t)(k0 + kl) * N + n0 + nl] : 0.f;
        sm.c.tl[kl][nl] = f2bf(v);
      }
      __syncthreads();
      // write rows of Bsw (coalesced in k), applying the chunk swizzle
      const int nl2 = tid >> 2, q = tid & 3;
      ushort8 o0, o1;
#pragma unroll
      for (int m = 0; m < 16; ++m) {
        const int cc = (q * 16 + m) >> 3, j = m & 7;
        const unsigned short val = sm.c.tl[((cc ^ (nl2 & 7)) << 3) + j][nl2];
        if (m < 8) o0[m] = val; else o1[m - 8] = val;
      }
      unsigned short* drow = Dst + (size_t)(n0 + nl2) * K2_N + k0 + q * 16;
      *(ushort8*)drow = o0;
      *(ushort8*)(drow + 8) = o1;
      __syncthreads();
    }
    return;
  }

  if (blockIdx.x < 16) {
    // ================= GRU branch: 16 samples per block =================
    const int j = tid & 7;
    const int b = blockIdx.x * 16 + (tid >> 4);

    const float* xsrc = X + (size_t)b * (T_N * IN_N) + MOE_RAW_N + j;
#pragma unroll
    for (int t = 0; t < T_N; ++t) {
      __builtin_amdgcn_global_load_lds((AS1Q unsigned int*)(xsrc + t * IN_N),
                                       (AS3Q unsigned int*)&sm.r.xl[t][wave * 64], 4, 0, 0);
    }

    const int got = __builtin_amdgcn_update_dpp(0, j, 0x121, 0xF, 0xF, true);
    const bool plus = (got == ((j + 1) & 7));

    // gather rotation-ordered weights into LDS: wl[mat*3+gate][j][r]
    if (tid < 64) {
      const int fj = tid >> 3, fr = tid & 7;
      const int idx = plus ? ((fj + fr) & 7) : ((fj - fr) & 7);
      const float* Wm[4] = {Wih0, Whh0, Wih1, Whh1};
#pragma unroll
      for (int mat = 0; mat < 4; ++mat)
#pragma unroll
        for (int gg = 0; gg < 3; ++gg)
          sm.r.wl[mat * 3 + gg][fj][fr] = Wm[mat][(gg * 8 + fj) * 8 + idx];
    }

    const float br0 = bih0[j] + bhh0[j], bz0 = bih0[8 + j] + bhh0[8 + j];
    const float bin0 = bih0[16 + j],     bhn0 = bhh0[16 + j];
    const float br1 = bih1[j] + bhh1[j], bz1 = bih1[8 + j] + bhh1[8 + j];
    const float bin1 = bih1[16 + j],     bhn1 = bhh1[16 + j];

    __syncthreads();   // xl (vmcnt) + wl (lgkmcnt) ready

    float h1 = 0.f, h2 = 0.f;
    float xcur = sm.r.xl[0][tid];

    auto dot8 = [&](int m, const float (&rv)[8], float& accA, float& accB) {
      const f32x4 w0 = *(const f32x4*)&sm.r.wl[m][j][0];
      const f32x4 w1v = *(const f32x4*)&sm.r.wl[m][j][4];
#pragma unroll
      for (int q = 0; q < 4; ++q) { accA += w0[q] * rv[q]; accB += w1v[q] * rv[4 + q]; }
    };

#pragma unroll 1
    for (int t = 0; t <= T_N; ++t) {   // 61 iterations (software pipeline)
      const float xnext = sm.r.xl[(t + 1 < T_N) ? t + 1 : T_N - 1][tid];

      float rx[8];  rot8(rx, xcur);
      float rh1[8]; rot8(rh1, h1);
      float rh2[8]; rot8(rh2, h2);

      float grA = br0, gzA = bz0, gnA = bin0, hnA = bhn0;
      float grB = 0.f, gzB = 0.f, gnB = 0.f, hnB = 0.f;
      dot8(0, rx, grA, grB); dot8(1, rx, gzA, gzB); dot8(2, rx, gnA, gnB);
      dot8(3, rh1, grA, grB); dot8(4, rh1, gzA, gzB); dot8(5, rh1, hnA, hnB);
      float h1n;
      {
        const float r0 = sigf(grA + grB), z0 = sigf(gzA + gzB);
        const float n0 = tanh_fast((gnA + gnB) + r0 * (hnA + hnB));
        h1n = (1.f - z0) * n0 + z0 * h1;
      }

      float grA1 = br1, gzA1 = bz1, gnA1 = bin1, hnA1 = bhn1;
      float grB1 = 0.f, gzB1 = 0.f, gnB1 = 0.f, hnB1 = 0.f;
      dot8(6, rh1, grA1, grB1); dot8(7, rh1, gzA1, gzB1); dot8(8, rh1, gnA1, gnB1);
      dot8(9, rh2, grA1, grB1); dot8(10, rh2, gzA1, gzB1); dot8(11, rh2, hnA1, hnB1);
      float h2n;
      {
        const float r1 = sigf(grA1 + grB1), z1 = sigf(gzA1 + gzB1);
        const float n1 = tanh_fast((gnA1 + gnB1) + r1 * (hnA1 + hnB1));
        h2n = (1.f - z1) * n1 + z1 * h2;
      }

      h1 = h1n;
      h2 = (t == 0) ? 0.f : h2n;
      xcur = xnext;
    }

    float rv[8]; rot8(rv, h2);
    float m = rv[0];
#pragma unroll
    for (int r = 1; r < 8; ++r) m = fmaxf(m, rv[r]);
    const float ej = __expf(h2 - m);
    float re[8]; rot8(re, ej);
    float sden = 0.f;
#pragma unroll
    for (int r = 0; r < 8; ++r) sden += re[r];
    if (!(tid & 8)) Omega[b * 8 + j] = __fdividef(ej, sden);
    return;
  }

  // ================= GEMM branch: Y1[sp][e] = Xm @ w1_e =================
  const int bid = blockIdx.x - 16;           // 0..191
  const int sp  = bid / 96;                  // 0..1
  const int rr0 = bid - sp * 96;
  const int e   = rr0 & 7;
  const int nt  = rr0 >> 3;                  // 0..11
  const int n0  = nt * 64;
  const int kt0 = sp * 8, kt1 = kt0 + 8;

  const int r15 = lane & 15, hi4 = lane >> 4, r7 = lane & 7;

  const unsigned short* Abase = XmBf + (size_t)(wave * 64 + (lane >> 3)) * KA_N + (lane & 7) * 8;
  const int bn = lane;
  const int kq = wave;
  const bool nvalid = (n0 + bn) < HID_N;
  const float* Bbase = w1 + ((size_t)e * MOE_IN_N + kq * 16) * HID_N + (n0 + bn);

  f32x4 acc[4][4];
  const f32x4 zero4 = {0.f, 0.f, 0.f, 0.f};
#pragma unroll
  for (int mi = 0; mi < 4; ++mi)
#pragma unroll
    for (int ni = 0; ni < 4; ++ni) acc[mi][ni] = zero4;

  auto stage = [&](int bufi, int kt) {
    const unsigned short* ga = Abase + kt * 64;
#pragma unroll
    for (int it = 0; it < 8; ++it) {
      __builtin_amdgcn_global_load_lds(
          (AS1Q unsigned int*)(ga + (size_t)it * 8 * KA_N),
          (AS3Q unsigned int*)&sm.g.Al[bufi][wave * 64 + it * 8][0],
          16, 0, 0);
    }
    const int kbase = kt * 64 + kq * 16;
    const float* gb = Bbase + (size_t)kt * 64 * HID_N;
    float v[16];
#pragma unroll
    for (int jj = 0; jj < 16; ++jj)
      v[jj] = (nvalid && (kbase + jj) < MOE_IN_N) ? gb[(size_t)jj * HID_N] : 0.f;
    ushort8 p0, p1;
#pragma unroll
    for (int jj = 0; jj < 8; ++jj) { p0[jj] = f2bf(v[jj]); p1[jj] = f2bf(v[jj + 8]); }
    const int sl0 = ((kq * 2) ^ (bn & 7)) * 8;
    const int sl1 = ((kq * 2 + 1) ^ (bn & 7)) * 8;
    *(ushort8*)&sm.g.Bl[bufi][bn][sl0] = p0;
    *(ushort8*)&sm.g.Bl[bufi][bn][sl1] = p1;
  };

  auto compute = [&](int bufi) {
#pragma unroll
    for (int ki = 0; ki < 2; ++ki) {
      const int ch = ((ki * 4 + hi4) ^ r7) * 8;
      short8 af[4], bfv[4];
#pragma unroll
      for (int mi = 0; mi < 4; ++mi)
        af[mi] = *(const short8*)&sm.g.Al[bufi][wave * 64 + mi * 16 + r15][ch];
#pragma unroll
      for (int ni = 0; ni < 4; ++ni)
        bfv[ni] = *(const short8*)&sm.g.Bl[bufi][ni * 16 + r15][ch];
#pragma unroll
      for (int mi = 0; mi < 4; ++mi)
#pragma unroll
        for (int ni = 0; ni < 4; ++ni)
          acc[mi][ni] = __builtin_amdgcn_mfma_f32_16x16x32_bf16(af[mi], bfv[ni], acc[mi][ni], 0, 0, 0);
    }
  };

  stage(0, kt0);
  __syncthreads();
  int buf = 0;
  for (int kt = kt0; kt < kt1; ++kt) {
    if (kt + 1 < kt1) stage(buf ^ 1, kt + 1);
    compute(buf);
    __syncthreads();
    buf ^= 1;
  }

  float* Pp = Y1 + ((size_t)(sp * 8 + e) * 256) * PN + n0;
#pragma unroll
  for (int mi = 0; mi < 4; ++mi) {
    const int row = wave * 64 + mi * 16 + hi4 * 4;
#pragma unroll
    for (int ni = 0; ni < 4; ++ni) {
#pragma unroll
      for (int rq = 0; rq < 4; ++rq)
        Pp[(size_t)(row + rq) * PN + ni * 16 + r15] = acc[mi][ni][rq];
    }
  }
}

// ---------------------------------------------------------------------------
// reduce1: a1 = elu( Sum_e Omega_e*(Y1[0][e]+Y1[1][e]) + Omega@b1 ) -> xt2.
// ---------------------------------------------------------------------------
__global__ __launch_bounds__(256)
void reduce1_mix(const float* __restrict__ Y1, const float* __restrict__ Omega,
                 const float* __restrict__ bias, unsigned short* __restrict__ xnext)
{
  const int n = blockIdx.x * 256 + threadIdx.x;
  const int b = blockIdx.y;
  if (n >= HID_N) return;
  float om[8];
#pragma unroll
  for (int e = 0; e < 8; ++e) om[e] = Omega[b * 8 + e];
  float acc = 0.f, bs = 0.f;
#pragma unroll
  for (int e = 0; e < 8; ++e) {
    const float ye = Y1[((size_t)e * 256 + b) * PN + n]
                   + Y1[((size_t)(8 + e) * 256 + b) * PN + n];
    acc += om[e] * ye;
    bs  += om[e] * bias[(size_t)e * HID_N + n];
  }
  const float y = acc + bs;
  const float a = (y > 0.f) ? y : expm1f(y);      // ELU
  const int swz = (b & 7) << 3;
  unsigned short* row = xnext + (size_t)b * K2_N;
#pragma unroll
  for (int e = 0; e < 8; ++e)
    row[(e * HID_N + n) ^ swz] = f2bf(om[e] * a);
}

// ---------------------------------------------------------------------------
// Split-K GEMM (R11-proven slab form, SPLITK=20) with B pre-converted to
// bf16 swizzled [n][k] (Bsw): B staging is now 2 global_load_lds per wave
// (lane-linear dest, per-lane src) — no fp32 gather, no in-loop cvt.
// ---------------------------------------------------------------------------
__global__ __launch_bounds__(256)
void gemm_splitk(const unsigned short* __restrict__ A,
                 const unsigned short* __restrict__ Bsw,
                 float* __restrict__ P,
                 int K, int N, int NPAD)
{
  __shared__ unsigned short Al[2][256][64];
  __shared__ unsigned short Bl[2][64][64];

  const int tid = threadIdx.x;
  const int lane = tid & 63;
  const int wave = tid >> 6;
  const int nt = blockIdx.x, sp = blockIdx.y;
  const int n0 = nt * 64;
  const int KT = K >> 6;
  const int kt0 = (KT * sp) / SPLITK;
  const int kt1 = (KT * (sp + 1)) / SPLITK;

  const int r15 = lane & 15, hi4 = lane >> 4, r7 = lane & 7;

  const unsigned short* Abase = A + (size_t)(wave * 64 + (lane >> 3)) * K + (lane & 7) * 8;
  // B staging: wave w iter it covers rows (w*2+it)*8 .. +8; lane l -> row +l>>3, chunk l&7
  const unsigned short* Bbase = Bsw + (size_t)(n0 + (wave * 2) * 8 + (lane >> 3)) * K2_N + (lane & 7) * 8;

  f32x4 acc[4][4];
  const f32x4 zero4 = {0.f, 0.f, 0.f, 0.f};
#pragma unroll
  for (int mi = 0; mi < 4; ++mi)
#pragma unroll
    for (int ni = 0; ni < 4; ++ni) acc[mi][ni] = zero4;

  auto stage = [&](int bufi, int kt) {
    const unsigned short* ga = Abase + kt * 64;
#pragma unroll
    for (int it = 0; it < 8; ++it) {
      __builtin_amdgcn_global_load_lds(
          (AS1Q unsigned int*)(ga + (size_t)it * 8 * K),
          (AS3Q unsigned int*)&Al[bufi][wave * 64 + it * 8][0],
          16, 0, 0);
    }
    const unsigned short* gbB = Bbase + kt * 64;
#pragma unroll
    for (int it = 0; it < 2; ++it) {
      __builtin_amdgcn_global_load_lds(
          (AS1Q unsigned int*)(gbB + (size_t)it * 8 * K2_N),
          (AS3Q unsigned int*)&Bl[bufi][(wave * 2 + it) * 8][0],
          16, 0, 0);
    }
  };

  auto compute = [&](int bufi) {
#pragma unroll
    for (int ki = 0; ki < 2; ++ki) {
      const int ch = ((ki * 4 + hi4) ^ r7) * 8;
      short8 af[4], bfv[4];
#pragma unroll
      for (int mi = 0; mi < 4; ++mi)
        af[mi] = *(const short8*)&Al[bufi][wave * 64 + mi * 16 + r15][ch];
#pragma unroll
      for (int ni = 0; ni < 4; ++ni)
        bfv[ni] = *(const short8*)&Bl[bufi][ni * 16 + r15][ch];
#pragma unroll
      for (int mi = 0; mi < 4; ++mi)
#pragma unroll
        for (int ni = 0; ni < 4; ++ni)
          acc[mi][ni] = __builtin_amdgcn_mfma_f32_16x16x32_bf16(af[mi], bfv[ni], acc[mi][ni], 0, 0, 0);
    }
  };

  stage(0, kt0);
  __syncthreads();
  int buf = 0;
  for (int kt = kt0; kt < kt1; ++kt) {
    if (kt + 1 < kt1) stage(buf ^ 1, kt + 1);
    compute(buf);
    __syncthreads();
    buf ^= 1;
  }

  float* Pp = P + (size_t)sp * 256 * NPAD + n0;
#pragma unroll
  for (int mi = 0; mi < 4; ++mi) {
    const int row = wave * 64 + mi * 16 + hi4 * 4;
#pragma unroll
    for (int ni = 0; ni < 4; ++ni) {
#pragma unroll
      for (int rq = 0; rq < 4; ++rq)
        Pp[(size_t)(row + rq) * NPAD + ni * 16 + r15] = acc[mi][ni][rq];
    }
  }
}

// ---------------------------------------------------------------------------
// Reduce split-K partials + Omega-blended bias; ELU+mix -> xnext, or final out.
// ---------------------------------------------------------------------------
__global__ __launch_bounds__(256)
void reduce_mix_kernel(const float* __restrict__ P, const float* __restrict__ Omega,
                       const float* __restrict__ bias, unsigned short* __restrict__ xnext,
                       float* __restrict__ Yout, int N, int NPAD)
{
  const int n = blockIdx.x * 256 + threadIdx.x;
  const int b = blockIdx.y;
  if (n >= N) return;
  float acc = 0.f;
#pragma unroll 4
  for (int s = 0; s < SPLITK; ++s) acc += P[((size_t)s * 256 + b) * NPAD + n];
  float om[8];
#pragma unroll
  for (int e = 0; e < 8; ++e) om[e] = Omega[b * 8 + e];
  float bs = 0.f;
#pragma unroll
  for (int e = 0; e < 8; ++e) bs += om[e] * bias[(size_t)e * N + n];
  float y = acc + bs;
  if (Yout) { Yout[(size_t)b * N + n] = y; return; }
  float a = (y > 0.f) ? y : expm1f(y);            // ELU
  const int swz = (b & 7) << 3;
  unsigned short* row = xnext + (size_t)b * K2_N;
#pragma unroll
  for (int e = 0; e < 8; ++e)
    row[(e * HID_N + n) ^ swz] = f2bf(om[e] * a);
}

// ---------------------------------------------------------------------------
extern "C" void kernel_launch(void* const* d_in, const int* in_sizes, int n_in,
                              void* d_out, int out_size, void* d_ws, size_t ws_size,
                              hipStream_t stream) {
  const float* X    = (const float*)d_in[0];
  const float* Wih0 = (const float*)d_in[1];
  const float* Whh0 = (const float*)d_in[2];
  const float* bih0 = (const float*)d_in[3];
  const float* bhh0 = (const float*)d_in[4];
  const float* Wih1 = (const float*)d_in[5];
  const float* Whh1 = (const float*)d_in[6];
  const float* bih1 = (const float*)d_in[7];
  const float* bhh1 = (const float*)d_in[8];
  const float* w1   = (const float*)d_in[9];
  const float* b1   = (const float*)d_in[10];
  const float* w2   = (const float*)d_in[11];
  const float* b2   = (const float*)d_in[12];
  const float* w3   = (const float*)d_in[13];
  const float* b3   = (const float*)d_in[14];

  char* ws = (char*)d_ws;
  float* Omega          = (float*)ws;                       // 8 KB
  unsigned short* XmBf  = (unsigned short*)(ws + 8192);     // 524,288
  unsigned short* xt2   = (unsigned short*)(ws + 532480);   // 3,080,192
  unsigned short* xt3   = (unsigned short*)(ws + 3612672);  // 3,080,192
  float* Y1             = (float*)(ws + 6692864);           // 12,582,912
  float* P              = (float*)(ws + 19275776);          // 20*256*768*4 = 15,728,640
  unsigned short* B2sw2 = (unsigned short*)(ws + 35004416); // 768*6016*2 = 9,240,576
  unsigned short* B2sw3 = (unsigned short*)(ws + 44244992); // 512*6016*2 = 6,160,384

  // Omega-free prep of bf16 Xm (swizzled, zero-padded to K=1024)
  xm_prep<<<dim3(4, 256), 256, 0, stream>>>(X, XmBf);

  // GRU (16) + expert GEMM1 (192) + w2/w3 bf16-swizzle conversion (48, idle CUs)
  fused_gru_gemm1<<<256, 256, 0, stream>>>(X, Wih0, Whh0, bih0, bhh0,
                                           Wih1, Whh1, bih1, bhh1,
                                           XmBf, w1, w2, w3, B2sw2, B2sw3,
                                           Y1, Omega);

  // fold Omega + bias + ELU -> xt2
  reduce1_mix<<<dim3(3, 256), 256, 0, stream>>>(Y1, Omega, b1, xt2);

  // layer 2: 256 x 6016 @ 6016 x 752  (slab split-K, bf16 pre-swizzled B)
  gemm_splitk<<<dim3(12, SPLITK), 256, 0, stream>>>(xt2, B2sw2, P, K2_N, HID_N, 768);
  reduce_mix_kernel<<<dim3(3, 256), 256, 0, stream>>>(P, Omega, b2, xt3, nullptr, HID_N, 768);

  // layer 3: 256 x 6016 @ 6016 x 512
  gemm_splitk<<<dim3(8, SPLITK), 256, 0, stream>>>(xt3, B2sw3, P, K2_N, 512, 512);
  reduce_mix_kernel<<<dim3(2, 256), 256, 0, stream>>>(P, Omega, b3, nullptr, (float*)d_out, 512, 512);
}

// Round 20
// 79.770 us; speedup vs baseline: 2.1052x; 2.1052x over previous
//
#include <hip/hip_runtime.h>
#include <cstdint>
#include <cstddef>

typedef __attribute__((ext_vector_type(8))) short short8;
typedef __attribute__((ext_vector_type(8))) unsigned short ushort8;
typedef __attribute__((ext_vector_type(4))) float f32x4;

#define AS1Q const __attribute__((address_space(1)))
#define AS3Q __attribute__((address_space(3)))

constexpr int T_N = 60, IN_N = 520, MOE_RAW_N = 512, MOE_IN_N = 992;
constexpr int HID_N = 752, E_N = 8;
constexpr int K2_N = 6016;            // 8*752
constexpr int KA_N = 1024;            // padded Xm row length (992 -> 1024)
constexpr int SPLITK = 20;            // R11-proven
constexpr int PN = 768;               // Y1 / P row pitch

static __device__ __forceinline__ unsigned short f2bf(float f) {
  unsigned int u = __float_as_uint(f);
  return (unsigned short)((u + 0x7fffu + ((u >> 16) & 1u)) >> 16);   // RNE
}
static __device__ __forceinline__ float sigf(float x) {
  return __fdividef(1.f, 1.f + __expf(-x));
}
static __device__ __forceinline__ float tanh_fast(float x) {
  return 2.f * __fdividef(1.f, 1.f + __expf(-2.f * x)) - 1.f;
}

// DPP row-rotate by R within the 16-lane row (pure VALU — no LDS pipe).
template<int R>
static __device__ __forceinline__ float rotf(float v) {
  return __int_as_float(__builtin_amdgcn_update_dpp(
      0, __float_as_int(v), 0x120 | R, 0xF, 0xF, true));
}
static __device__ __forceinline__ void rot8(float (&d)[8], float v) {
  d[0] = v;
  d[1] = rotf<1>(v); d[2] = rotf<2>(v); d[3] = rotf<3>(v);
  d[4] = rotf<4>(v); d[5] = rotf<5>(v); d[6] = rotf<6>(v); d[7] = rotf<7>(v);
}

// ---------------------------------------------------------------------------
// xm_prep: Xm_bf16[b][ (i ^ (b&7)<<3) ] = bf16(Xm[b,i]), rows padded to 1024.
// ---------------------------------------------------------------------------
__global__ __launch_bounds__(256)
void xm_prep(const float* __restrict__ X, unsigned short* __restrict__ XmBf)
{
  const int i = blockIdx.x * 256 + threadIdx.x;   // grid.x=4 -> 0..1023
  const int b = blockIdx.y;
  const float* Xb = X + (size_t)b * (T_N * IN_N);
  float v = 0.f;
  if (i < MOE_RAW_N) {
    v = Xb[(T_N - 1) * IN_N + i];
  } else if (i < MOE_IN_N) {
    const int q = i - MOE_RAW_N;
    v = Xb[(q >> 3) * IN_N + MOE_RAW_N + (q & 7)];
  }
  XmBf[(size_t)b * KA_N + (i ^ ((b & 7) << 3))] = f2bf(v);
}

// ---------------------------------------------------------------------------
// FUSED: GRU (blocks 0..63) + expert-separated layer-1 GEMM (blocks 64..255).
// ROUND-20 GRU FIX: ONE GRU WAVE PER CU. R11's GRU ran 4 waves/CU, each
// issuing 24 ds_read_b128/iter -> 96 x ~12cy = ~1150cy/iter of serialized
// LDS-pipe time (matches the measured ~1400cy/iter that survived R4-R11;
// issue floor is only ~260cy). Now: 64 GRU blocks x 4 samples, only wave 0
// active (waves 1-3 exit before any barrier; same-wave s_waitcnt replaces
// __syncthreads). LDS pipe per CU serves ONE wave -> ~4x less contention.
// Arithmetic bit-identical to R11. GEMM branch + tail verbatim R11.
// ---------------------------------------------------------------------------
__global__ __launch_bounds__(256, 1)
void fused_gru_gemm1(const float* __restrict__ X,
                     const float* __restrict__ Wih0, const float* __restrict__ Whh0,
                     const float* __restrict__ bih0, const float* __restrict__ bhh0,
                     const float* __restrict__ Wih1, const float* __restrict__ Whh1,
                     const float* __restrict__ bih1, const float* __restrict__ bhh1,
                     const unsigned short* __restrict__ XmBf,
                     const float* __restrict__ w1,
                     float* __restrict__ Y1, float* __restrict__ Omega)
{
  __shared__ union SM {
    struct { unsigned short Al[2][256][64]; unsigned short Bl[2][64][64]; } g; // 80 KB
    struct { float xl[T_N][64]; float wl[12][8][8]; } r;                       // 18.4 KB
  } sm;

  const int tid  = threadIdx.x;
  const int lane = tid & 63;
  const int wave = tid >> 6;

  if (blockIdx.x < 64) {
    // ================= GRU branch: 4 samples, ONE wave =================
    if (wave != 0) return;             // waves 1-3: no barrier anywhere -> safe

    const int j = tid & 7;
    const int b = blockIdx.x * 4 + (tid >> 4);

    const float* xsrc = X + (size_t)b * (T_N * IN_N) + MOE_RAW_N + j;
#pragma unroll
    for (int t = 0; t < T_N; ++t) {
      __builtin_amdgcn_global_load_lds((AS1Q unsigned int*)(xsrc + t * IN_N),
                                       (AS3Q unsigned int*)&sm.r.xl[t][0], 4, 0, 0);
    }

    const int got = __builtin_amdgcn_update_dpp(0, j, 0x121, 0xF, 0xF, true);
    const bool plus = (got == ((j + 1) & 7));

    // gather rotation-ordered weights into LDS: wl[mat*3+gate][j][r]
    {
      const int fj = tid >> 3, fr = tid & 7;     // tid < 64 here
      const int idx = plus ? ((fj + fr) & 7) : ((fj - fr) & 7);
      const float* Wm[4] = {Wih0, Whh0, Wih1, Whh1};
#pragma unroll
      for (int mat = 0; mat < 4; ++mat)
#pragma unroll
        for (int gg = 0; gg < 3; ++gg)
          sm.r.wl[mat * 3 + gg][fj][fr] = Wm[mat][(gg * 8 + fj) * 8 + idx];
    }

    const float br0 = bih0[j] + bhh0[j], bz0 = bih0[8 + j] + bhh0[8 + j];
    const float bin0 = bih0[16 + j],     bhn0 = bhh0[16 + j];
    const float br1 = bih1[j] + bhh1[j], bz1 = bih1[8 + j] + bhh1[8 + j];
    const float bin1 = bih1[16 + j],     bhn1 = bhh1[16 + j];

    // single wave: drain global_load_lds (vmcnt) + ds_writes (lgkmcnt)
    asm volatile("s_waitcnt vmcnt(0) lgkmcnt(0)" ::: "memory");

    float h1 = 0.f, h2 = 0.f;
    float xcur = sm.r.xl[0][tid];

    auto dot8 = [&](int m, const float (&rv)[8], float& accA, float& accB) {
      const f32x4 w0 = *(const f32x4*)&sm.r.wl[m][j][0];
      const f32x4 w1v = *(const f32x4*)&sm.r.wl[m][j][4];
#pragma unroll
      for (int q = 0; q < 4; ++q) { accA += w0[q] * rv[q]; accB += w1v[q] * rv[4 + q]; }
    };

#pragma unroll 1
    for (int t = 0; t <= T_N; ++t) {   // 61 iterations (software pipeline)
      const float xnext = sm.r.xl[(t + 1 < T_N) ? t + 1 : T_N - 1][tid];

      float rx[8];  rot8(rx, xcur);
      float rh1[8]; rot8(rh1, h1);
      float rh2[8]; rot8(rh2, h2);

      float grA = br0, gzA = bz0, gnA = bin0, hnA = bhn0;
      float grB = 0.f, gzB = 0.f, gnB = 0.f, hnB = 0.f;
      dot8(0, rx, grA, grB); dot8(1, rx, gzA, gzB); dot8(2, rx, gnA, gnB);
      dot8(3, rh1, grA, grB); dot8(4, rh1, gzA, gzB); dot8(5, rh1, hnA, hnB);
      float h1n;
      {
        const float r0 = sigf(grA + grB), z0 = sigf(gzA + gzB);
        const float n0 = tanh_fast((gnA + gnB) + r0 * (hnA + hnB));
        h1n = (1.f - z0) * n0 + z0 * h1;
      }

      float grA1 = br1, gzA1 = bz1, gnA1 = bin1, hnA1 = bhn1;
      float grB1 = 0.f, gzB1 = 0.f, gnB1 = 0.f, hnB1 = 0.f;
      dot8(6, rh1, grA1, grB1); dot8(7, rh1, gzA1, gzB1); dot8(8, rh1, gnA1, gnB1);
      dot8(9, rh2, grA1, grB1); dot8(10, rh2, gzA1, gzB1); dot8(11, rh2, hnA1, hnB1);
      float h2n;
      {
        const float r1 = sigf(grA1 + grB1), z1 = sigf(gzA1 + gzB1);
        const float n1 = tanh_fast((gnA1 + gnB1) + r1 * (hnA1 + hnB1));
        h2n = (1.f - z1) * n1 + z1 * h2;
      }

      h1 = h1n;
      h2 = (t == 0) ? 0.f : h2n;
      xcur = xnext;
    }

    float rv[8]; rot8(rv, h2);
    float m = rv[0];
#pragma unroll
    for (int r = 1; r < 8; ++r) m = fmaxf(m, rv[r]);
    const float ej = __expf(h2 - m);
    float re[8]; rot8(re, ej);
    float sden = 0.f;
#pragma unroll
    for (int r = 0; r < 8; ++r) sden += re[r];
    if (!(tid & 8)) Omega[b * 8 + j] = __fdividef(ej, sden);
    return;
  }

  // ================= GEMM branch: Y1[sp][e] = Xm @ w1_e =================
  const int bid = blockIdx.x - 64;           // 0..191
  const int sp  = bid / 96;                  // 0..1
  const int rr0 = bid - sp * 96;
  const int e   = rr0 & 7;
  const int nt  = rr0 >> 3;                  // 0..11
  const int n0  = nt * 64;
  const int kt0 = sp * 8, kt1 = kt0 + 8;

  const int r15 = lane & 15, hi4 = lane >> 4, r7 = lane & 7;

  const unsigned short* Abase = XmBf + (size_t)(wave * 64 + (lane >> 3)) * KA_N + (lane & 7) * 8;
  const int bn = lane;
  const int kq = wave;
  const bool nvalid = (n0 + bn) < HID_N;
  const float* Bbase = w1 + ((size_t)e * MOE_IN_N + kq * 16) * HID_N + (n0 + bn);

  f32x4 acc[4][4];
  const f32x4 zero4 = {0.f, 0.f, 0.f, 0.f};
#pragma unroll
  for (int mi = 0; mi < 4; ++mi)
#pragma unroll
    for (int ni = 0; ni < 4; ++ni) acc[mi][ni] = zero4;

  auto stage = [&](int bufi, int kt) {
    const unsigned short* ga = Abase + kt * 64;
#pragma unroll
    for (int it = 0; it < 8; ++it) {
      __builtin_amdgcn_global_load_lds(
          (AS1Q unsigned int*)(ga + (size_t)it * 8 * KA_N),
          (AS3Q unsigned int*)&sm.g.Al[bufi][wave * 64 + it * 8][0],
          16, 0, 0);
    }
    const int kbase = kt * 64 + kq * 16;
    const float* gb = Bbase + (size_t)kt * 64 * HID_N;
    float v[16];
#pragma unroll
    for (int jj = 0; jj < 16; ++jj)
      v[jj] = (nvalid && (kbase + jj) < MOE_IN_N) ? gb[(size_t)jj * HID_N] : 0.f;
    ushort8 p0, p1;
#pragma unroll
    for (int jj = 0; jj < 8; ++jj) { p0[jj] = f2bf(v[jj]); p1[jj] = f2bf(v[jj + 8]); }
    const int sl0 = ((kq * 2) ^ (bn & 7)) * 8;
    const int sl1 = ((kq * 2 + 1) ^ (bn & 7)) * 8;
    *(ushort8*)&sm.g.Bl[bufi][bn][sl0] = p0;
    *(ushort8*)&sm.g.Bl[bufi][bn][sl1] = p1;
  };

  auto compute = [&](int bufi) {
#pragma unroll
    for (int ki = 0; ki < 2; ++ki) {
      const int ch = ((ki * 4 + hi4) ^ r7) * 8;
      short8 af[4], bfv[4];
#pragma unroll
      for (int mi = 0; mi < 4; ++mi)
        af[mi] = *(const short8*)&sm.g.Al[bufi][wave * 64 + mi * 16 + r15][ch];
#pragma unroll
      for (int ni = 0; ni < 4; ++ni)
        bfv[ni] = *(const short8*)&sm.g.Bl[bufi][ni * 16 + r15][ch];
#pragma unroll
      for (int mi = 0; mi < 4; ++mi)
#pragma unroll
        for (int ni = 0; ni < 4; ++ni)
          acc[mi][ni] = __builtin_amdgcn_mfma_f32_16x16x32_bf16(af[mi], bfv[ni], acc[mi][ni], 0, 0, 0);
    }
  };

  stage(0, kt0);
  __syncthreads();
  int buf = 0;
  for (int kt = kt0; kt < kt1; ++kt) {
    if (kt + 1 < kt1) stage(buf ^ 1, kt + 1);
    compute(buf);
    __syncthreads();
    buf ^= 1;
  }

  float* Pp = Y1 + ((size_t)(sp * 8 + e) * 256) * PN + n0;
#pragma unroll
  for (int mi = 0; mi < 4; ++mi) {
    const int row = wave * 64 + mi * 16 + hi4 * 4;
#pragma unroll
    for (int ni = 0; ni < 4; ++ni) {
#pragma unroll
      for (int rq = 0; rq < 4; ++rq)
        Pp[(size_t)(row + rq) * PN + ni * 16 + r15] = acc[mi][ni][rq];
    }
  }
}

// ---------------------------------------------------------------------------
// reduce1: a1 = elu( Sum_e Omega_e*(Y1[0][e]+Y1[1][e]) + Omega@b1 ) -> xt2.
// ---------------------------------------------------------------------------
__global__ __launch_bounds__(256)
void reduce1_mix(const float* __restrict__ Y1, const float* __restrict__ Omega,
                 const float* __restrict__ bias, unsigned short* __restrict__ xnext)
{
  const int n = blockIdx.x * 256 + threadIdx.x;
  const int b = blockIdx.y;
  if (n >= HID_N) return;
  float om[8];
#pragma unroll
  for (int e = 0; e < 8; ++e) om[e] = Omega[b * 8 + e];
  float acc = 0.f, bs = 0.f;
#pragma unroll
  for (int e = 0; e < 8; ++e) {
    const float ye = Y1[((size_t)e * 256 + b) * PN + n]
                   + Y1[((size_t)(8 + e) * 256 + b) * PN + n];
    acc += om[e] * ye;
    bs  += om[e] * bias[(size_t)e * HID_N + n];
  }
  const float y = acc + bs;
  const float a = (y > 0.f) ? y : expm1f(y);      // ELU
  const int swz = (b & 7) << 3;
  unsigned short* row = xnext + (size_t)b * K2_N;
#pragma unroll
  for (int e = 0; e < 8; ++e)
    row[(e * HID_N + n) ^ swz] = f2bf(om[e] * a);
}

// ---------------------------------------------------------------------------
// Split-K GEMM (R11-proven slab form, SPLITK=20, fp32 B gather staging).
// ---------------------------------------------------------------------------
__global__ __launch_bounds__(256)
void gemm_splitk(const unsigned short* __restrict__ A,
                 const float* __restrict__ Bw,
                 float* __restrict__ P,
                 int K, int N, int NPAD)
{
  __shared__ unsigned short Al[2][256][64];
  __shared__ unsigned short Bl[2][64][64];

  const int tid = threadIdx.x;
  const int lane = tid & 63;
  const int wave = tid >> 6;
  const int nt = blockIdx.x, sp = blockIdx.y;
  const int n0 = nt * 64;
  const int KT = K >> 6;
  const int kt0 = (KT * sp) / SPLITK;
  const int kt1 = (KT * (sp + 1)) / SPLITK;

  const int r15 = lane & 15, hi4 = lane >> 4, r7 = lane & 7;

  const unsigned short* Abase = A + (size_t)(wave * 64 + (lane >> 3)) * K + (lane & 7) * 8;
  const int bn = lane;
  const int kq = wave;
  const bool nvalid = (n0 + bn) < N;
  const float* Bbase = Bw + (size_t)(kq * 16) * N + (n0 + bn);

  f32x4 acc[4][4];
  const f32x4 zero4 = {0.f, 0.f, 0.f, 0.f};
#pragma unroll
  for (int mi = 0; mi < 4; ++mi)
#pragma unroll
    for (int ni = 0; ni < 4; ++ni) acc[mi][ni] = zero4;

  auto stage = [&](int bufi, int kt) {
    const unsigned short* ga = Abase + kt * 64;
#pragma unroll
    for (int it = 0; it < 8; ++it) {
      __builtin_amdgcn_global_load_lds(
          (AS1Q unsigned int*)(ga + (size_t)it * 8 * K),
          (AS3Q unsigned int*)&Al[bufi][wave * 64 + it * 8][0],
          16, 0, 0);
    }
    const float* gb = Bbase + (size_t)kt * 64 * N;
    float v[16];
#pragma unroll
    for (int jj = 0; jj < 16; ++jj) v[jj] = nvalid ? gb[(size_t)jj * N] : 0.f;
    ushort8 p0, p1;
#pragma unroll
    for (int jj = 0; jj < 8; ++jj) { p0[jj] = f2bf(v[jj]); p1[jj] = f2bf(v[jj + 8]); }
    const int sl0 = ((kq * 2) ^ (bn & 7)) * 8;
    const int sl1 = ((kq * 2 + 1) ^ (bn & 7)) * 8;
    *(ushort8*)&Bl[bufi][bn][sl0] = p0;
    *(ushort8*)&Bl[bufi][bn][sl1] = p1;
  };

  auto compute = [&](int bufi) {
#pragma unroll
    for (int ki = 0; ki < 2; ++ki) {
      const int ch = ((ki * 4 + hi4) ^ r7) * 8;
      short8 af[4], bfv[4];
#pragma unroll
      for (int mi = 0; mi < 4; ++mi)
        af[mi] = *(const short8*)&Al[bufi][wave * 64 + mi * 16 + r15][ch];
#pragma unroll
      for (int ni = 0; ni < 4; ++ni)
        bfv[ni] = *(const short8*)&Bl[bufi][ni * 16 + r15][ch];
#pragma unroll
      for (int mi = 0; mi < 4; ++mi)
#pragma unroll
        for (int ni = 0; ni < 4; ++ni)
          acc[mi][ni] = __builtin_amdgcn_mfma_f32_16x16x32_bf16(af[mi], bfv[ni], acc[mi][ni], 0, 0, 0);
    }
  };

  stage(0, kt0);
  __syncthreads();
  int buf = 0;
  for (int kt = kt0; kt < kt1; ++kt) {
    if (kt + 1 < kt1) stage(buf ^ 1, kt + 1);
    compute(buf);
    __syncthreads();
    buf ^= 1;
  }

  float* Pp = P + (size_t)sp * 256 * NPAD + n0;
#pragma unroll
  for (int mi = 0; mi < 4; ++mi) {
    const int row = wave * 64 + mi * 16 + hi4 * 4;
#pragma unroll
    for (int ni = 0; ni < 4; ++ni) {
#pragma unroll
      for (int rq = 0; rq < 4; ++rq)
        Pp[(size_t)(row + rq) * NPAD + ni * 16 + r15] = acc[mi][ni][rq];
    }
  }
}

// ---------------------------------------------------------------------------
// Reduce split-K partials + Omega-blended bias; ELU+mix -> xnext, or final out.
// ---------------------------------------------------------------------------
__global__ __launch_bounds__(256)
void reduce_mix_kernel(const float* __restrict__ P, const float* __restrict__ Omega,
                       const float* __restrict__ bias, unsigned short* __restrict__ xnext,
                       float* __restrict__ Yout, int N, int NPAD)
{
  const int n = blockIdx.x * 256 + threadIdx.x;
  const int b = blockIdx.y;
  if (n >= N) return;
  float acc = 0.f;
#pragma unroll 4
  for (int s = 0; s < SPLITK; ++s) acc += P[((size_t)s * 256 + b) * NPAD + n];
  float om[8];
#pragma unroll
  for (int e = 0; e < 8; ++e) om[e] = Omega[b * 8 + e];
  float bs = 0.f;
#pragma unroll
  for (int e = 0; e < 8; ++e) bs += om[e] * bias[(size_t)e * N + n];
  float y = acc + bs;
  if (Yout) { Yout[(size_t)b * N + n] = y; return; }
  float a = (y > 0.f) ? y : expm1f(y);            // ELU
  const int swz = (b & 7) << 3;
  unsigned short* row = xnext + (size_t)b * K2_N;
#pragma unroll
  for (int e = 0; e < 8; ++e)
    row[(e * HID_N + n) ^ swz] = f2bf(om[e] * a);
}

// ---------------------------------------------------------------------------
extern "C" void kernel_launch(void* const* d_in, const int* in_sizes, int n_in,
                              void* d_out, int out_size, void* d_ws, size_t ws_size,
                              hipStream_t stream) {
  const float* X    = (const float*)d_in[0];
  const float* Wih0 = (const float*)d_in[1];
  const float* Whh0 = (const float*)d_in[2];
  const float* bih0 = (const float*)d_in[3];
  const float* bhh0 = (const float*)d_in[4];
  const float* Wih1 = (const float*)d_in[5];
  const float* Whh1 = (const float*)d_in[6];
  const float* bih1 = (const float*)d_in[7];
  const float* bhh1 = (const float*)d_in[8];
  const float* w1   = (const float*)d_in[9];
  const float* b1   = (const float*)d_in[10];
  const float* w2   = (const float*)d_in[11];
  const float* b2   = (const float*)d_in[12];
  const float* w3   = (const float*)d_in[13];
  const float* b3   = (const float*)d_in[14];

  char* ws = (char*)d_ws;
  float* Omega         = (float*)ws;                      // 8 KB
  unsigned short* XmBf = (unsigned short*)(ws + 8192);    // 524,288
  unsigned short* xt2  = (unsigned short*)(ws + 532480);  // 3,080,192
  unsigned short* xt3  = (unsigned short*)(ws + 3612672); // 3,080,192
  float* Y1            = (float*)(ws + 6692864);          // 12,582,912
  float* P             = (float*)(ws + 19275776);         // 15,728,640

  // Omega-free prep of bf16 Xm (swizzled, zero-padded to K=1024)
  xm_prep<<<dim3(4, 256), 256, 0, stream>>>(X, XmBf);

  // GRU (64 blocks, 1 wave each) + expert GEMM1 (192 blocks)
  fused_gru_gemm1<<<256, 256, 0, stream>>>(X, Wih0, Whh0, bih0, bhh0,
                                           Wih1, Whh1, bih1, bhh1,
                                           XmBf, w1, Y1, Omega);

  // fold Omega + bias + ELU -> xt2
  reduce1_mix<<<dim3(3, 256), 256, 0, stream>>>(Y1, Omega, b1, xt2);

  // layer 2: 256 x 6016 @ 6016 x 752  (slab split-K, R11-proven)
  gemm_splitk<<<dim3(12, SPLITK), 256, 0, stream>>>(xt2, w2, P, K2_N, HID_N, 768);
  reduce_mix_kernel<<<dim3(3, 256), 256, 0, stream>>>(P, Omega, b2, xt3, nullptr, HID_N, 768);

  // layer 3: 256 x 6016 @ 6016 x 512
  gemm_splitk<<<dim3(8, SPLITK), 256, 0, stream>>>(xt3, w3, P, K2_N, 512, 512);
  reduce_mix_kernel<<<dim3(2, 256), 256, 0, stream>>>(P, Omega, b3, nullptr, (float*)d_out, 512, 512);
}